// Round 1
// baseline (467.370 us; speedup 1.0000x reference)
//
#include <hip/hip_runtime.h>

#define NNODES 20000
#define BATCH  2
#define FEAT   256
#define OOUT   64
#define PBLK   200

// ---------- edge dtype detect (int64 vs int32) ----------
__global__ void detect_kernel(const int* __restrict__ raw, int* __restrict__ flag, int E) {
  __shared__ int any;
  if (threadIdx.x == 0) any = 0;
  __syncthreads();
  int nchk = E < 2048 ? E : 2048;
  for (int i = threadIdx.x; i < nchk; i += blockDim.x)
    if (raw[2 * i + 1] != 0) any = 1;   // int64 high words are 0 (values < 20000)
  __syncthreads();
  if (threadIdx.x == 0) *flag = any;    // 1 => int32 layout, 0 => int64 layout
}

__global__ void convert_kernel(const int* __restrict__ raw, const int* __restrict__ flag,
                               int* __restrict__ s32, int* __restrict__ d32, int E) {
  int e = blockIdx.x * blockDim.x + threadIdx.x;
  if (e >= E) return;
  if (*flag) { s32[e] = raw[e];     d32[e] = raw[E + e]; }
  else       { s32[e] = raw[2 * e]; d32[e] = raw[2 * (E + e)]; }
}

// ---------- degree / norm ----------
__global__ void count_kernel(const int* __restrict__ d32, int* __restrict__ cnt, int E) {
  int e = blockIdx.x * blockDim.x + threadIdx.x;
  if (e < E) atomicAdd(&cnt[d32[e]], 1);
}

__global__ void dinv_kernel(const int* __restrict__ cnt, float* __restrict__ dinv, int n) {
  int i = blockIdx.x * blockDim.x + threadIdx.x;
  if (i < n) dinv[i] = 1.0f / sqrtf((float)(cnt[i] + 1));
}

// single-block scan over counts -> exclusive row_start
__global__ __launch_bounds__(1024) void scan_kernel(const int* __restrict__ cnt,
                                                    int* __restrict__ row_start, int n) {
  __shared__ int sdata[1024];
  __shared__ int carry_s;
  int tid = threadIdx.x;
  if (tid == 0) carry_s = 0;
  __syncthreads();
  for (int base = 0; base < n; base += 1024) {
    int carry = carry_s;
    int v = (base + tid < n) ? cnt[base + tid] : 0;
    sdata[tid] = v;
    __syncthreads();
    for (int off = 1; off < 1024; off <<= 1) {
      int t = (tid >= off) ? sdata[tid - off] : 0;
      __syncthreads();
      sdata[tid] += t;
      __syncthreads();
    }
    if (base + tid < n) row_start[base + tid] = carry + sdata[tid] - v;
    if (tid == 0) carry_s = carry + sdata[1023];
    __syncthreads();
  }
  if (tid == 0) row_start[n] = carry_s;
}

__global__ void scatter_kernel(const int* __restrict__ s32, const int* __restrict__ d32,
                               const int* __restrict__ row_start, int* __restrict__ fill,
                               const float* __restrict__ dinv,
                               int* __restrict__ csr_src, float* __restrict__ csr_norm, int E) {
  int e = blockIdx.x * blockDim.x + threadIdx.x;
  if (e >= E) return;
  int s = s32[e], d = d32[e];
  int p = row_start[d] + atomicAdd(&fill[d], 1);
  csr_src[p] = s;
  csr_norm[p] = dinv[s] * dinv[d];
}

// ---------- GEMM f32: C[M,N] = A[M,K] @ B[K,N]; 64x64x16 tiles, 256 thr, 4x4/thread ----------
#define BM 64
#define BN 64
#define BK 16
__global__ __launch_bounds__(256) void gemm_f32(const float* __restrict__ A, const float* __restrict__ B,
                                                float* __restrict__ C, int M, int K, int N) {
  __shared__ float As[BK][BM];   // transposed A tile
  __shared__ float Bs[BK][BN];
  int tid = threadIdx.x;
  int bm = blockIdx.x * BM, bn = blockIdx.y * BN;
  int tx = tid & 15, ty = tid >> 4;
  int arow = tid >> 2, acol = (tid & 3) * 4;
  int brow = tid >> 4, bcol = (tid & 15) * 4;
  float acc[4][4] = {};
  for (int k0 = 0; k0 < K; k0 += BK) {
    float4 av = *(const float4*)&A[(size_t)(bm + arow) * K + k0 + acol];
    As[acol + 0][arow] = av.x;
    As[acol + 1][arow] = av.y;
    As[acol + 2][arow] = av.z;
    As[acol + 3][arow] = av.w;
    *(float4*)&Bs[brow][bcol] = *(const float4*)&B[(size_t)(k0 + brow) * N + bn + bcol];
    __syncthreads();
#pragma unroll
    for (int kk = 0; kk < BK; ++kk) {
      float4 a4 = *(const float4*)&As[kk][ty * 4];
      float4 b4 = *(const float4*)&Bs[kk][tx * 4];
      float a[4] = {a4.x, a4.y, a4.z, a4.w};
      float b[4] = {b4.x, b4.y, b4.z, b4.w};
#pragma unroll
      for (int i = 0; i < 4; ++i)
#pragma unroll
        for (int j = 0; j < 4; ++j)
          acc[i][j] = fmaf(a[i], b[j], acc[i][j]);
    }
    __syncthreads();
  }
#pragma unroll
  for (int i = 0; i < 4; ++i) {
    float4 o = make_float4(acc[i][0], acc[i][1], acc[i][2], acc[i][3]);
    *(float4*)&C[(size_t)(bm + ty * 4 + i) * N + bn + tx * 4] = o;
  }
}

// ---------- aggregation: out[b,n,:] = relu(bias + dinv[n]^2*h[b,n,:] + sum_e norm*h[b,src,:]) ----------
__global__ __launch_bounds__(128) void agg_kernel(const float* __restrict__ h, const int* __restrict__ row_start,
                                                  const int* __restrict__ csr_src, const float* __restrict__ csr_norm,
                                                  const float* __restrict__ dinv, const float* __restrict__ bias,
                                                  float* __restrict__ out) {
  int n = blockIdx.x;
  int b = threadIdx.x >> 6;          // wave 0 -> batch 0, wave 1 -> batch 1
  int c = (threadIdx.x & 63) * 4;
  const float* hb = h + (size_t)b * NNODES * FEAT;
  float di = dinv[n];
  float sn = di * di;
  float4 v = *(const float4*)&hb[(size_t)n * FEAT + c];
  float4 acc = make_float4(v.x * sn, v.y * sn, v.z * sn, v.w * sn);
  int s0 = row_start[n], s1 = row_start[n + 1];
  for (int i = s0; i < s1; ++i) {
    int s = csr_src[i];
    float w = csr_norm[i];
    float4 m = *(const float4*)&hb[(size_t)s * FEAT + c];
    acc.x = fmaf(w, m.x, acc.x);
    acc.y = fmaf(w, m.y, acc.y);
    acc.z = fmaf(w, m.z, acc.z);
    acc.w = fmaf(w, m.w, acc.w);
  }
  float4 bi = *(const float4*)&bias[c];
  acc.x = fmaxf(acc.x + bi.x, 0.0f);
  acc.y = fmaxf(acc.y + bi.y, 0.0f);
  acc.z = fmaxf(acc.z + bi.z, 0.0f);
  acc.w = fmaxf(acc.w + bi.w, 0.0f);
  *(float4*)&out[((size_t)b * NNODES + n) * FEAT + c] = acc;
}

// ---------- pooling (two-stage deterministic) + FC ----------
__global__ __launch_bounds__(256) void pool_partial(const float* __restrict__ h2,
                                                    float* __restrict__ partials) {
  int blk = blockIdx.x;
  int c = threadIdx.x;
  int chunk = NNODES / PBLK;          // 100
  int n0 = blk * chunk;
  float s0 = 0.f, s1 = 0.f;
  for (int n = n0; n < n0 + chunk; ++n) {
    s0 += h2[((size_t)0 * NNODES + n) * FEAT + c];
    s1 += h2[((size_t)1 * NNODES + n) * FEAT + c];
  }
  partials[(blk * 2 + 0) * FEAT + c] = s0;
  partials[(blk * 2 + 1) * FEAT + c] = s1;
}

__global__ __launch_bounds__(256) void pool_fc(const float* __restrict__ partials,
                                               const float* __restrict__ Wfc, const float* __restrict__ bfc,
                                               float* __restrict__ out) {
  __shared__ float pooled[BATCH][FEAT];
  int t = threadIdx.x;  // channel
  float s0 = 0.f, s1 = 0.f;
  for (int p = 0; p < PBLK; ++p) {
    s0 += partials[(p * 2 + 0) * FEAT + t];
    s1 += partials[(p * 2 + 1) * FEAT + t];
  }
  pooled[0][t] = s0 / (float)NNODES;
  pooled[1][t] = s1 / (float)NNODES;
  __syncthreads();
  if (t < BATCH * OOUT) {
    int b = t >> 6, o = t & 63;
    float acc = bfc[o];
    for (int c2 = 0; c2 < FEAT; ++c2)
      acc = fmaf(pooled[b][c2], Wfc[c2 * OOUT + o], acc);
    out[b * OOUT + o] = acc;
  }
}

extern "C" void kernel_launch(void* const* d_in, const int* in_sizes, int n_in,
                              void* d_out, int out_size, void* d_ws, size_t ws_size,
                              hipStream_t stream) {
  const float* x    = (const float*)d_in[0];
  const float* W1   = (const float*)d_in[1];
  const float* b1   = (const float*)d_in[2];
  const float* W2   = (const float*)d_in[3];
  const float* b2   = (const float*)d_in[4];
  const float* Wfc  = (const float*)d_in[5];
  const float* bfc  = (const float*)d_in[6];
  const int*   eraw = (const int*)d_in[7];
  int E = in_sizes[7] / 2;
  float* out = (float*)d_out;

  char* ws = (char*)d_ws;
  size_t off = 0;
  auto alloc = [&](size_t elems) -> void* {
    void* p = ws + off * 4;
    off += (elems + 3) & ~(size_t)3;   // keep 16B alignment for float4
    return p;
  };
  int*   flag      = (int*)alloc(4);
  int*   s32       = (int*)alloc(E);
  int*   d32       = (int*)alloc(E);
  int*   cnt       = (int*)alloc(NNODES);
  float* dinv      = (float*)alloc(NNODES);
  int*   row_start = (int*)alloc(NNODES + 1);
  int*   fill      = (int*)alloc(NNODES);
  int*   csr_src   = (int*)alloc(E);
  float* csr_norm  = (float*)alloc(E);
  float* bufA      = (float*)alloc((size_t)BATCH * NNODES * FEAT);
  float* bufB      = (float*)alloc((size_t)BATCH * NNODES * FEAT);
  float* partials  = (float*)alloc((size_t)PBLK * BATCH * FEAT);

  hipMemsetAsync(cnt, 0, NNODES * sizeof(int), stream);
  hipMemsetAsync(fill, 0, NNODES * sizeof(int), stream);

  int eg = (E + 255) / 256;
  detect_kernel<<<1, 256, 0, stream>>>(eraw, flag, E);
  convert_kernel<<<eg, 256, 0, stream>>>(eraw, flag, s32, d32, E);
  count_kernel<<<eg, 256, 0, stream>>>(d32, cnt, E);
  dinv_kernel<<<(NNODES + 255) / 256, 256, 0, stream>>>(cnt, dinv, NNODES);
  scan_kernel<<<1, 1024, 0, stream>>>(cnt, row_start, NNODES);
  scatter_kernel<<<eg, 256, 0, stream>>>(s32, d32, row_start, fill, dinv, csr_src, csr_norm, E);

  int M = BATCH * NNODES;  // 40000, divisible by 64
  dim3 ggrid(M / BM, FEAT / BN);
  gemm_f32<<<ggrid, 256, 0, stream>>>(x, W1, bufA, M, FEAT, FEAT);
  agg_kernel<<<NNODES, 128, 0, stream>>>(bufA, row_start, csr_src, csr_norm, dinv, b1, bufB);
  gemm_f32<<<ggrid, 256, 0, stream>>>(bufB, W2, bufA, M, FEAT, FEAT);
  agg_kernel<<<NNODES, 128, 0, stream>>>(bufA, row_start, csr_src, csr_norm, dinv, b2, bufB);
  pool_partial<<<PBLK, 256, 0, stream>>>(bufB, partials);
  pool_fc<<<1, 256, 0, stream>>>(partials, Wfc, bfc, out);
}

// Round 2
// 350.363 us; speedup vs baseline: 1.3340x; 1.3340x over previous
//
#include <hip/hip_runtime.h>

#define NNODES 20000
#define BATCH  2
#define FEAT   256
#define OOUT   64
#define PBLK   200

// ---------- bf16 helpers ----------
__device__ __forceinline__ float bf2f(unsigned short u) {
  return __uint_as_float(((unsigned int)u) << 16);
}
__device__ __forceinline__ unsigned short f2bf(float f) {  // round-to-nearest-even
  unsigned int u = __float_as_uint(f);
  return (unsigned short)((u + 0x7fffu + ((u >> 16) & 1u)) >> 16);
}

// ---------- edge dtype detect (int64 vs int32) ----------
__global__ void detect_kernel(const int* __restrict__ raw, int* __restrict__ flag, int E) {
  __shared__ int any;
  if (threadIdx.x == 0) any = 0;
  __syncthreads();
  int nchk = E < 2048 ? E : 2048;
  for (int i = threadIdx.x; i < nchk; i += blockDim.x)
    if (raw[2 * i + 1] != 0) any = 1;   // int64 high words are 0 (values < 20000)
  __syncthreads();
  if (threadIdx.x == 0) *flag = any;    // 1 => int32 layout, 0 => int64 layout
}

__global__ void convert_kernel(const int* __restrict__ raw, const int* __restrict__ flag,
                               int* __restrict__ s32, int* __restrict__ d32, int E) {
  int e = blockIdx.x * blockDim.x + threadIdx.x;
  if (e >= E) return;
  if (*flag) { s32[e] = raw[e];     d32[e] = raw[E + e]; }
  else       { s32[e] = raw[2 * e]; d32[e] = raw[2 * (E + e)]; }
}

// ---------- degree / norm ----------
__global__ void count_kernel(const int* __restrict__ d32, int* __restrict__ cnt, int E) {
  int e = blockIdx.x * blockDim.x + threadIdx.x;
  if (e < E) atomicAdd(&cnt[d32[e]], 1);
}

__global__ void dinv_kernel(const int* __restrict__ cnt, float* __restrict__ dinv, int n) {
  int i = blockIdx.x * blockDim.x + threadIdx.x;
  if (i < n) dinv[i] = 1.0f / sqrtf((float)(cnt[i] + 1));
}

// single-block scan over counts -> exclusive row_start (wave-shfl based, 3 barriers/chunk)
__global__ __launch_bounds__(1024) void scan_kernel(const int* __restrict__ cnt,
                                                    int* __restrict__ row_start, int n) {
  __shared__ int wsum[16];
  __shared__ int carry_s;
  int tid = threadIdx.x, lane = tid & 63, wv = tid >> 6;
  if (tid == 0) carry_s = 0;
  __syncthreads();
  for (int base = 0; base < n; base += 1024) {
    int v = (base + tid < n) ? cnt[base + tid] : 0;
    int x = v;                              // inclusive wave scan
#pragma unroll
    for (int off = 1; off < 64; off <<= 1) {
      int t = __shfl_up(x, off);
      if (lane >= off) x += t;
    }
    if (lane == 63) wsum[wv] = x;
    __syncthreads();                        // (A) wsum visible; prev carry write visible
    int carry = carry_s;
    if (wv == 0) {
      int s = (lane < 16) ? wsum[lane] : 0;
#pragma unroll
      for (int off = 1; off < 16; off <<= 1) {
        int t = __shfl_up(s, off);
        if (lane >= off) s += t;
      }
      if (lane < 16) wsum[lane] = s;        // inclusive scan of wave sums
    }
    __syncthreads();                        // (B)
    int woff = wv ? wsum[wv - 1] : 0;
    int total = wsum[15];
    if (base + tid < n) row_start[base + tid] = carry + woff + x - v;
    __syncthreads();                        // (C) all reads done
    if (tid == 0) carry_s = carry + total;
  }
  if (tid == 0) row_start[n] = carry_s;
}

__global__ void scatter_kernel(const int* __restrict__ s32, const int* __restrict__ d32,
                               const int* __restrict__ row_start, int* __restrict__ fill,
                               const float* __restrict__ dinv,
                               int* __restrict__ csr_src, float* __restrict__ csr_norm, int E) {
  int e = blockIdx.x * blockDim.x + threadIdx.x;
  if (e >= E) return;
  int s = s32[e], d = d32[e];
  int p = row_start[d] + atomicAdd(&fill[d], 1);
  csr_src[p] = s;
  csr_norm[p] = dinv[s] * dinv[d];
}

// ---------- GEMM f32 -> bf16 out: C[M,N] = A[M,K] @ B[K,N]; 64x64x16 tiles ----------
#define BM 64
#define BN 64
#define BK 16
__global__ __launch_bounds__(256) void gemm_f32(const float* __restrict__ A, const float* __restrict__ B,
                                                unsigned short* __restrict__ C, int M, int K, int N) {
  __shared__ float As[BK][BM];   // transposed A tile
  __shared__ float Bs[BK][BN];
  int tid = threadIdx.x;
  int bm = blockIdx.x * BM, bn = blockIdx.y * BN;
  int tx = tid & 15, ty = tid >> 4;
  int arow = tid >> 2, acol = (tid & 3) * 4;
  int brow = tid >> 4, bcol = (tid & 15) * 4;
  float acc[4][4] = {};
  for (int k0 = 0; k0 < K; k0 += BK) {
    float4 av = *(const float4*)&A[(size_t)(bm + arow) * K + k0 + acol];
    As[acol + 0][arow] = av.x;
    As[acol + 1][arow] = av.y;
    As[acol + 2][arow] = av.z;
    As[acol + 3][arow] = av.w;
    *(float4*)&Bs[brow][bcol] = *(const float4*)&B[(size_t)(k0 + brow) * N + bn + bcol];
    __syncthreads();
#pragma unroll
    for (int kk = 0; kk < BK; ++kk) {
      float4 a4 = *(const float4*)&As[kk][ty * 4];
      float4 b4 = *(const float4*)&Bs[kk][tx * 4];
      float a[4] = {a4.x, a4.y, a4.z, a4.w};
      float b[4] = {b4.x, b4.y, b4.z, b4.w};
#pragma unroll
      for (int i = 0; i < 4; ++i)
#pragma unroll
        for (int j = 0; j < 4; ++j)
          acc[i][j] = fmaf(a[i], b[j], acc[i][j]);
    }
    __syncthreads();
  }
#pragma unroll
  for (int i = 0; i < 4; ++i) {
    ushort4 o;
    o.x = f2bf(acc[i][0]);
    o.y = f2bf(acc[i][1]);
    o.z = f2bf(acc[i][2]);
    o.w = f2bf(acc[i][3]);
    *(ushort4*)&C[(size_t)(bm + ty * 4 + i) * N + bn + tx * 4] = o;
  }
}

// ---------- aggregation: out[b,n,:] = relu(bias + dinv[n]^2*h[b,n,:] + sum_e norm*h[b,src,:]) ----------
// h is bf16; accumulate fp32; out fp32.
__global__ __launch_bounds__(128) void agg_kernel(const unsigned short* __restrict__ h,
                                                  const int* __restrict__ row_start,
                                                  const int* __restrict__ csr_src,
                                                  const float* __restrict__ csr_norm,
                                                  const float* __restrict__ dinv,
                                                  const float* __restrict__ bias,
                                                  float* __restrict__ out) {
  int n = blockIdx.x;
  int b = threadIdx.x >> 6;          // wave 0 -> batch 0, wave 1 -> batch 1
  int c = (threadIdx.x & 63) * 4;
  const unsigned short* hb = h + (size_t)b * NNODES * FEAT;
  float di = dinv[n];
  float sn = di * di;
  ushort4 v = *(const ushort4*)&hb[(size_t)n * FEAT + c];
  float4 acc = make_float4(bf2f(v.x) * sn, bf2f(v.y) * sn, bf2f(v.z) * sn, bf2f(v.w) * sn);
  int s0 = row_start[n], s1 = row_start[n + 1];
  int i = s0;
  for (; i + 2 <= s1; i += 2) {
    int sa = csr_src[i], sb = csr_src[i + 1];
    float wa = csr_norm[i], wb = csr_norm[i + 1];
    ushort4 ma = *(const ushort4*)&hb[(size_t)sa * FEAT + c];
    ushort4 mb = *(const ushort4*)&hb[(size_t)sb * FEAT + c];
    acc.x = fmaf(wa, bf2f(ma.x), acc.x);
    acc.y = fmaf(wa, bf2f(ma.y), acc.y);
    acc.z = fmaf(wa, bf2f(ma.z), acc.z);
    acc.w = fmaf(wa, bf2f(ma.w), acc.w);
    acc.x = fmaf(wb, bf2f(mb.x), acc.x);
    acc.y = fmaf(wb, bf2f(mb.y), acc.y);
    acc.z = fmaf(wb, bf2f(mb.z), acc.z);
    acc.w = fmaf(wb, bf2f(mb.w), acc.w);
  }
  if (i < s1) {
    int s = csr_src[i];
    float w = csr_norm[i];
    ushort4 m = *(const ushort4*)&hb[(size_t)s * FEAT + c];
    acc.x = fmaf(w, bf2f(m.x), acc.x);
    acc.y = fmaf(w, bf2f(m.y), acc.y);
    acc.z = fmaf(w, bf2f(m.z), acc.z);
    acc.w = fmaf(w, bf2f(m.w), acc.w);
  }
  float4 bi = *(const float4*)&bias[c];
  acc.x = fmaxf(acc.x + bi.x, 0.0f);
  acc.y = fmaxf(acc.y + bi.y, 0.0f);
  acc.z = fmaxf(acc.z + bi.z, 0.0f);
  acc.w = fmaxf(acc.w + bi.w, 0.0f);
  *(float4*)&out[((size_t)b * NNODES + n) * FEAT + c] = acc;
}

// ---------- pooling (two-stage deterministic) + FC ----------
__global__ __launch_bounds__(256) void pool_partial(const float* __restrict__ h2,
                                                    float* __restrict__ partials) {
  int blk = blockIdx.x;
  int c = threadIdx.x;
  int chunk = NNODES / PBLK;          // 100
  int n0 = blk * chunk;
  float s0 = 0.f, s1 = 0.f;
  for (int n = n0; n < n0 + chunk; ++n) {
    s0 += h2[((size_t)0 * NNODES + n) * FEAT + c];
    s1 += h2[((size_t)1 * NNODES + n) * FEAT + c];
  }
  partials[(blk * 2 + 0) * FEAT + c] = s0;
  partials[(blk * 2 + 1) * FEAT + c] = s1;
}

__global__ __launch_bounds__(256) void pool_fc(const float* __restrict__ partials,
                                               const float* __restrict__ Wfc, const float* __restrict__ bfc,
                                               float* __restrict__ out) {
  __shared__ float pooled[BATCH][FEAT];
  int t = threadIdx.x;  // channel
  float s0 = 0.f, s1 = 0.f;
  for (int p = 0; p < PBLK; ++p) {
    s0 += partials[(p * 2 + 0) * FEAT + t];
    s1 += partials[(p * 2 + 1) * FEAT + t];
  }
  pooled[0][t] = s0 / (float)NNODES;
  pooled[1][t] = s1 / (float)NNODES;
  __syncthreads();
  if (t < BATCH * OOUT) {
    int b = t >> 6, o = t & 63;
    float acc = bfc[o];
    for (int c2 = 0; c2 < FEAT; ++c2)
      acc = fmaf(pooled[b][c2], Wfc[c2 * OOUT + o], acc);
    out[b * OOUT + o] = acc;
  }
}

extern "C" void kernel_launch(void* const* d_in, const int* in_sizes, int n_in,
                              void* d_out, int out_size, void* d_ws, size_t ws_size,
                              hipStream_t stream) {
  const float* x    = (const float*)d_in[0];
  const float* W1   = (const float*)d_in[1];
  const float* b1   = (const float*)d_in[2];
  const float* W2   = (const float*)d_in[3];
  const float* b2   = (const float*)d_in[4];
  const float* Wfc  = (const float*)d_in[5];
  const float* bfc  = (const float*)d_in[6];
  const int*   eraw = (const int*)d_in[7];
  int E = in_sizes[7] / 2;
  float* out = (float*)d_out;

  char* ws = (char*)d_ws;
  size_t off = 0;
  auto alloc = [&](size_t elems) -> void* {   // elems in 4-byte units
    void* p = ws + off * 4;
    off += (elems + 3) & ~(size_t)3;          // keep 16B alignment
    return p;
  };
  int*   flag      = (int*)alloc(4);
  int*   s32       = (int*)alloc(E);
  int*   d32       = (int*)alloc(E);
  int*   cnt       = (int*)alloc(NNODES);
  float* dinv      = (float*)alloc(NNODES);
  int*   row_start = (int*)alloc(NNODES + 1);
  int*   fill      = (int*)alloc(NNODES);
  int*   csr_src   = (int*)alloc(E);
  float* csr_norm  = (float*)alloc(E);
  unsigned short* hbf = (unsigned short*)alloc((size_t)BATCH * NNODES * FEAT / 2);  // bf16 h
  float* a1        = (float*)alloc((size_t)BATCH * NNODES * FEAT);                  // fp32 agg out
  float* partials  = (float*)alloc((size_t)PBLK * BATCH * FEAT);

  hipMemsetAsync(cnt, 0, NNODES * sizeof(int), stream);
  hipMemsetAsync(fill, 0, NNODES * sizeof(int), stream);

  int eg = (E + 255) / 256;
  detect_kernel<<<1, 256, 0, stream>>>(eraw, flag, E);
  convert_kernel<<<eg, 256, 0, stream>>>(eraw, flag, s32, d32, E);
  count_kernel<<<eg, 256, 0, stream>>>(d32, cnt, E);
  dinv_kernel<<<(NNODES + 255) / 256, 256, 0, stream>>>(cnt, dinv, NNODES);
  scan_kernel<<<1, 1024, 0, stream>>>(cnt, row_start, NNODES);
  scatter_kernel<<<eg, 256, 0, stream>>>(s32, d32, row_start, fill, dinv, csr_src, csr_norm, E);

  int M = BATCH * NNODES;  // 40000, divisible by 64
  dim3 ggrid(M / BM, FEAT / BN);
  gemm_f32<<<ggrid, 256, 0, stream>>>(x, W1, hbf, M, FEAT, FEAT);
  agg_kernel<<<NNODES, 128, 0, stream>>>(hbf, row_start, csr_src, csr_norm, dinv, b1, a1);
  gemm_f32<<<ggrid, 256, 0, stream>>>(a1, W2, hbf, M, FEAT, FEAT);
  agg_kernel<<<NNODES, 128, 0, stream>>>(hbf, row_start, csr_src, csr_norm, dinv, b2, a1);
  pool_partial<<<PBLK, 256, 0, stream>>>(a1, partials);
  pool_fc<<<1, 256, 0, stream>>>(partials, Wfc, bfc, out);
}

// Round 3
// 266.725 us; speedup vs baseline: 1.7523x; 1.3136x over previous
//
#include <hip/hip_runtime.h>

#define NNODES 20000
#define BATCH  2
#define FEAT   256
#define OOUT   64
#define PBLK   200
#define MROWS  (BATCH * NNODES)   // 40000
#define MPAD   40064              // 626 * 64

typedef short  bhalf8 __attribute__((ext_vector_type(8)));   // 8 bf16 in 4 VGPRs
typedef float  floatx4 __attribute__((ext_vector_type(4)));

// ---------- bf16 helpers ----------
__device__ __forceinline__ float bf2f(unsigned short u) {
  return __uint_as_float(((unsigned int)u) << 16);
}
__device__ __forceinline__ unsigned short f2bf(float f) {  // round-to-nearest-even
  unsigned int u = __float_as_uint(f);
  return (unsigned short)((u + 0x7fffu + ((u >> 16) & 1u)) >> 16);
}

// ---------- edge dtype detect (int64 vs int32) ----------
__global__ void detect_kernel(const int* __restrict__ raw, int* __restrict__ flag, int E) {
  __shared__ int any;
  if (threadIdx.x == 0) any = 0;
  __syncthreads();
  int nchk = E < 2048 ? E : 2048;
  for (int i = threadIdx.x; i < nchk; i += blockDim.x)
    if (raw[2 * i + 1] != 0) any = 1;   // int64 high words are 0 (values < 20000)
  __syncthreads();
  if (threadIdx.x == 0) *flag = any;    // 1 => int32 layout, 0 => int64 layout
}

__global__ void convert_kernel(const int* __restrict__ raw, const int* __restrict__ flag,
                               int* __restrict__ s32, int* __restrict__ d32, int E) {
  int e = blockIdx.x * blockDim.x + threadIdx.x;
  if (e >= E) return;
  if (*flag) { s32[e] = raw[e];     d32[e] = raw[E + e]; }
  else       { s32[e] = raw[2 * e]; d32[e] = raw[2 * (E + e)]; }
}

// ---------- degree / norm ----------
__global__ void count_kernel(const int* __restrict__ d32, int* __restrict__ cnt, int E) {
  int e = blockIdx.x * blockDim.x + threadIdx.x;
  if (e < E) atomicAdd(&cnt[d32[e]], 1);
}

__global__ void dinv_kernel(const int* __restrict__ cnt, float* __restrict__ dinv, int n) {
  int i = blockIdx.x * blockDim.x + threadIdx.x;
  if (i < n) dinv[i] = 1.0f / sqrtf((float)(cnt[i] + 1));
}

// single-block scan over counts -> exclusive row_start (wave-shfl based)
__global__ __launch_bounds__(1024) void scan_kernel(const int* __restrict__ cnt,
                                                    int* __restrict__ row_start, int n) {
  __shared__ int wsum[16];
  __shared__ int carry_s;
  int tid = threadIdx.x, lane = tid & 63, wv = tid >> 6;
  if (tid == 0) carry_s = 0;
  __syncthreads();
  for (int base = 0; base < n; base += 1024) {
    int v = (base + tid < n) ? cnt[base + tid] : 0;
    int x = v;                              // inclusive wave scan
#pragma unroll
    for (int off = 1; off < 64; off <<= 1) {
      int t = __shfl_up(x, off);
      if (lane >= off) x += t;
    }
    if (lane == 63) wsum[wv] = x;
    __syncthreads();
    int carry = carry_s;
    if (wv == 0) {
      int s = (lane < 16) ? wsum[lane] : 0;
#pragma unroll
      for (int off = 1; off < 16; off <<= 1) {
        int t = __shfl_up(s, off);
        if (lane >= off) s += t;
      }
      if (lane < 16) wsum[lane] = s;
    }
    __syncthreads();
    int woff = wv ? wsum[wv - 1] : 0;
    int total = wsum[15];
    if (base + tid < n) row_start[base + tid] = carry + woff + x - v;
    __syncthreads();
    if (tid == 0) carry_s = carry + total;
  }
  if (tid == 0) row_start[n] = carry_s;
}

__global__ void scatter_kernel(const int* __restrict__ s32, const int* __restrict__ d32,
                               const int* __restrict__ row_start, int* __restrict__ fill,
                               const float* __restrict__ dinv,
                               int* __restrict__ csr_src, float* __restrict__ csr_norm, int E) {
  int e = blockIdx.x * blockDim.x + threadIdx.x;
  if (e >= E) return;
  int s = s32[e], d = d32[e];
  int p = row_start[d] + atomicAdd(&fill[d], 1);
  csr_src[p] = s;
  csr_norm[p] = dinv[s] * dinv[d];
}

// ---------- W prep: fp32 W[k][n] -> bf16 hi/lo, pre-shuffled into MFMA fragment order ----------
// A-operand frag (W as X in mfma(X,Y,acc)): lane = kchunk*16 + (n&15) holds 8 contiguous k
// slice layout: elem addr = ((ks*16 + g)*64 + lane)*8 + j   (ks=k>>5, g=n>>4, j=k&7)
__global__ __launch_bounds__(256) void wprep_kernel(const float* __restrict__ W,
                                                    unsigned short* __restrict__ Whi,
                                                    unsigned short* __restrict__ Wlo) {
  int idx = blockIdx.x * 256 + threadIdx.x;   // idx = k*256 + n  (64K threads)
  int k = idx >> 8, n = idx & 255;
  float w = W[idx];
  unsigned short hi = f2bf(w);
  unsigned short lo = f2bf(w - bf2f(hi));
  int g = n >> 4, ln = n & 15;
  int ks = k >> 5, ch = (k >> 3) & 3, j = k & 7;
  int addr = ((ks * 16 + g) * 64 + ch * 16 + ln) * 8 + j;
  Whi[addr] = hi;
  Wlo[addr] = lo;
}

// ---------- MFMA GEMM: C[M,256] = A[M,256] @ W, A fp32 (layer1) or bf16 (layer2) ----------
// swapped operands: acc = mfma(W_frag, A_frag) -> D[n_local][m_local]
// 4 waves/block, 16 rows/wave, full N=256 (16 groups), BK=32, LDS dbuf (hi+lo) = 64 KiB
template <int AFP32>
__global__ __launch_bounds__(256) void gemm_mfma(const void* __restrict__ Av,
                                                 const unsigned short* __restrict__ Whi,
                                                 const unsigned short* __restrict__ Wlo,
                                                 unsigned short* __restrict__ C) {
  __shared__ unsigned short lds_arr[32768];   // 2 bufs x (hi 8192 + lo 8192) ushorts
  int tid = threadIdx.x, lane = tid & 63, wv = tid >> 6;
  int m0 = blockIdx.x * 64 + wv * 16;
  int mrow = m0 + (lane & 15);
  if (mrow >= MROWS) mrow = MROWS - 1;        // clamp pad rows (output ignored)
  int kc = (lane >> 4) * 8;                   // k-chunk offset within BK=32

  const float* Af          = (const float*)Av;
  const unsigned short* Ab = (const unsigned short*)Av;

  floatx4 acc[16];
#pragma unroll
  for (int g = 0; g < 16; ++g) acc[g] = (floatx4)(0.0f);

  bhalf8 st[8];  // staging regs: 4 hi + 4 lo chunks of 16B per thread

  auto stage_load = [&](int ks) {
#pragma unroll
    for (int i = 0; i < 4; ++i)
      st[i] = *(const bhalf8*)&Whi[(size_t)ks * 8192 + (i * 256 + tid) * 8];
#pragma unroll
    for (int i = 0; i < 4; ++i)
      st[4 + i] = *(const bhalf8*)&Wlo[(size_t)ks * 8192 + (i * 256 + tid) * 8];
  };
  auto stage_write = [&](int b) {
    unsigned short* base = &lds_arr[b * 16384];
#pragma unroll
    for (int i = 0; i < 4; ++i)
      *(bhalf8*)&base[(i * 256 + tid) * 8] = st[i];
#pragma unroll
    for (int i = 0; i < 4; ++i)
      *(bhalf8*)&base[8192 + (i * 256 + tid) * 8] = st[4 + i];
  };
  auto load_a = [&](int ks) -> bhalf8 {
    bhalf8 r;
    if (AFP32) {
      const float* p = &Af[(size_t)mrow * FEAT + ks * 32 + kc];
      float4 u = *(const float4*)p;
      float4 v = *(const float4*)(p + 4);
      r[0] = (short)f2bf(u.x); r[1] = (short)f2bf(u.y);
      r[2] = (short)f2bf(u.z); r[3] = (short)f2bf(u.w);
      r[4] = (short)f2bf(v.x); r[5] = (short)f2bf(v.y);
      r[6] = (short)f2bf(v.z); r[7] = (short)f2bf(v.w);
    } else {
      r = *(const bhalf8*)&Ab[(size_t)mrow * FEAT + ks * 32 + kc];
    }
    return r;
  };

  stage_load(0);
  stage_write(0);
  __syncthreads();
  int cur = 0;
  for (int ks = 0; ks < 8; ++ks) {
    if (ks < 7) stage_load(ks + 1);           // global loads in flight under compute
    bhalf8 a = load_a(ks);
    const unsigned short* bb = &lds_arr[cur * 16384];
#pragma unroll
    for (int g = 0; g < 16; ++g) {
      bhalf8 bh = *(const bhalf8*)&bb[g * 512 + lane * 8];          // contiguous: conflict-free
      bhalf8 bl = *(const bhalf8*)&bb[8192 + g * 512 + lane * 8];
      acc[g] = __builtin_amdgcn_mfma_f32_16x16x32_bf16(bh, a, acc[g], 0, 0, 0);
      acc[g] = __builtin_amdgcn_mfma_f32_16x16x32_bf16(bl, a, acc[g], 0, 0, 0);
    }
    if (ks < 7) stage_write(cur ^ 1);
    __syncthreads();
    cur ^= 1;
  }

  // D layout: m_local = lane&15, n_local = (lane>>4)*4 + reg
  int om = m0 + (lane & 15);                  // < MPAD, C is padded
  int nc = (lane >> 4) * 4;
#pragma unroll
  for (int g = 0; g < 16; ++g) {
    ushort4 o;
    o.x = f2bf(acc[g][0]); o.y = f2bf(acc[g][1]);
    o.z = f2bf(acc[g][2]); o.w = f2bf(acc[g][3]);
    *(ushort4*)&C[(size_t)om * FEAT + g * 16 + nc] = o;
  }
}

// ---------- aggregation: out[b,n,:] = relu(bias + dinv^2*h[n] + sum norm*h[src]) ; h,out bf16 ----------
__global__ __launch_bounds__(128) void agg_kernel(const unsigned short* __restrict__ h,
                                                  const int* __restrict__ row_start,
                                                  const int* __restrict__ csr_src,
                                                  const float* __restrict__ csr_norm,
                                                  const float* __restrict__ dinv,
                                                  const float* __restrict__ bias,
                                                  unsigned short* __restrict__ out) {
  int n = blockIdx.x;
  int b = threadIdx.x >> 6;          // wave 0 -> batch 0, wave 1 -> batch 1
  int c = (threadIdx.x & 63) * 4;
  const unsigned short* hb = h + (size_t)b * NNODES * FEAT;
  float di = dinv[n];
  float sn = di * di;
  ushort4 v = *(const ushort4*)&hb[(size_t)n * FEAT + c];
  float4 acc = make_float4(bf2f(v.x) * sn, bf2f(v.y) * sn, bf2f(v.z) * sn, bf2f(v.w) * sn);
  int s0 = row_start[n], s1 = row_start[n + 1];
  int i = s0;
  for (; i + 2 <= s1; i += 2) {
    int sa = csr_src[i], sb = csr_src[i + 1];
    float wa = csr_norm[i], wb = csr_norm[i + 1];
    ushort4 ma = *(const ushort4*)&hb[(size_t)sa * FEAT + c];
    ushort4 mb = *(const ushort4*)&hb[(size_t)sb * FEAT + c];
    acc.x = fmaf(wa, bf2f(ma.x), acc.x);
    acc.y = fmaf(wa, bf2f(ma.y), acc.y);
    acc.z = fmaf(wa, bf2f(ma.z), acc.z);
    acc.w = fmaf(wa, bf2f(ma.w), acc.w);
    acc.x = fmaf(wb, bf2f(mb.x), acc.x);
    acc.y = fmaf(wb, bf2f(mb.y), acc.y);
    acc.z = fmaf(wb, bf2f(mb.z), acc.z);
    acc.w = fmaf(wb, bf2f(mb.w), acc.w);
  }
  if (i < s1) {
    int s = csr_src[i];
    float w = csr_norm[i];
    ushort4 m = *(const ushort4*)&hb[(size_t)s * FEAT + c];
    acc.x = fmaf(w, bf2f(m.x), acc.x);
    acc.y = fmaf(w, bf2f(m.y), acc.y);
    acc.z = fmaf(w, bf2f(m.z), acc.z);
    acc.w = fmaf(w, bf2f(m.w), acc.w);
  }
  float4 bi = *(const float4*)&bias[c];
  ushort4 o;
  o.x = f2bf(fmaxf(acc.x + bi.x, 0.0f));
  o.y = f2bf(fmaxf(acc.y + bi.y, 0.0f));
  o.z = f2bf(fmaxf(acc.z + bi.z, 0.0f));
  o.w = f2bf(fmaxf(acc.w + bi.w, 0.0f));
  *(ushort4*)&out[((size_t)b * NNODES + n) * FEAT + c] = o;
}

// ---------- pooling (two-stage deterministic) + FC ----------
__global__ __launch_bounds__(256) void pool_partial(const unsigned short* __restrict__ h2,
                                                    float* __restrict__ partials) {
  int blk = blockIdx.x;
  int c = threadIdx.x;
  int chunk = NNODES / PBLK;          // 100
  int n0 = blk * chunk;
  float s0 = 0.f, s1 = 0.f;
  for (int n = n0; n < n0 + chunk; ++n) {
    s0 += bf2f(h2[((size_t)0 * NNODES + n) * FEAT + c]);
    s1 += bf2f(h2[((size_t)1 * NNODES + n) * FEAT + c]);
  }
  partials[(blk * 2 + 0) * FEAT + c] = s0;
  partials[(blk * 2 + 1) * FEAT + c] = s1;
}

__global__ __launch_bounds__(256) void pool_fc(const float* __restrict__ partials,
                                               const float* __restrict__ Wfc, const float* __restrict__ bfc,
                                               float* __restrict__ out) {
  __shared__ float pooled[BATCH][FEAT];
  int t = threadIdx.x;  // channel
  float s0 = 0.f, s1 = 0.f;
  for (int p = 0; p < PBLK; ++p) {
    s0 += partials[(p * 2 + 0) * FEAT + t];
    s1 += partials[(p * 2 + 1) * FEAT + t];
  }
  pooled[0][t] = s0 / (float)NNODES;
  pooled[1][t] = s1 / (float)NNODES;
  __syncthreads();
  if (t < BATCH * OOUT) {
    int b = t >> 6, o = t & 63;
    float acc = bfc[o];
    for (int c2 = 0; c2 < FEAT; ++c2)
      acc = fmaf(pooled[b][c2], Wfc[c2 * OOUT + o], acc);
    out[b * OOUT + o] = acc;
  }
}

extern "C" void kernel_launch(void* const* d_in, const int* in_sizes, int n_in,
                              void* d_out, int out_size, void* d_ws, size_t ws_size,
                              hipStream_t stream) {
  const float* x    = (const float*)d_in[0];
  const float* W1   = (const float*)d_in[1];
  const float* b1   = (const float*)d_in[2];
  const float* W2   = (const float*)d_in[3];
  const float* b2   = (const float*)d_in[4];
  const float* Wfc  = (const float*)d_in[5];
  const float* bfc  = (const float*)d_in[6];
  const int*   eraw = (const int*)d_in[7];
  int E = in_sizes[7] / 2;
  float* out = (float*)d_out;

  char* ws = (char*)d_ws;
  size_t off = 0;
  auto alloc = [&](size_t elems) -> void* {   // elems in 4-byte units
    void* p = ws + off * 4;
    off += (elems + 3) & ~(size_t)3;          // keep 16B alignment
    return p;
  };
  int*   flag      = (int*)alloc(4);
  int*   s32       = (int*)alloc(E);
  int*   d32       = (int*)alloc(E);
  int*   cnt       = (int*)alloc(NNODES);
  float* dinv      = (float*)alloc(NNODES);
  int*   row_start = (int*)alloc(NNODES + 1);
  int*   fill      = (int*)alloc(NNODES);
  int*   csr_src   = (int*)alloc(E);
  float* csr_norm  = (float*)alloc(E);
  unsigned short* w1hi = (unsigned short*)alloc(65536 / 2);
  unsigned short* w1lo = (unsigned short*)alloc(65536 / 2);
  unsigned short* w2hi = (unsigned short*)alloc(65536 / 2);
  unsigned short* w2lo = (unsigned short*)alloc(65536 / 2);
  unsigned short* hbf  = (unsigned short*)alloc((size_t)MPAD * FEAT / 2);    // padded GEMM out, bf16
  unsigned short* a1   = (unsigned short*)alloc((size_t)MROWS * FEAT / 2);   // agg out, bf16
  float* partials  = (float*)alloc((size_t)PBLK * BATCH * FEAT);

  hipMemsetAsync(cnt, 0, NNODES * sizeof(int), stream);
  hipMemsetAsync(fill, 0, NNODES * sizeof(int), stream);

  int eg = (E + 255) / 256;
  detect_kernel<<<1, 256, 0, stream>>>(eraw, flag, E);
  convert_kernel<<<eg, 256, 0, stream>>>(eraw, flag, s32, d32, E);
  count_kernel<<<eg, 256, 0, stream>>>(d32, cnt, E);
  dinv_kernel<<<(NNODES + 255) / 256, 256, 0, stream>>>(cnt, dinv, NNODES);
  scan_kernel<<<1, 1024, 0, stream>>>(cnt, row_start, NNODES);
  scatter_kernel<<<eg, 256, 0, stream>>>(s32, d32, row_start, fill, dinv, csr_src, csr_norm, E);

  wprep_kernel<<<256, 256, 0, stream>>>(W1, w1hi, w1lo);
  wprep_kernel<<<256, 256, 0, stream>>>(W2, w2hi, w2lo);

  gemm_mfma<1><<<MPAD / 64, 256, 0, stream>>>(x, w1hi, w1lo, hbf);
  agg_kernel<<<NNODES, 128, 0, stream>>>(hbf, row_start, csr_src, csr_norm, dinv, b1, a1);
  gemm_mfma<0><<<MPAD / 64, 256, 0, stream>>>(a1, w2hi, w2lo, hbf);
  agg_kernel<<<NNODES, 128, 0, stream>>>(hbf, row_start, csr_src, csr_norm, dinv, b2, a1);
  pool_partial<<<PBLK, 256, 0, stream>>>(a1, partials);
  pool_fc<<<1, 256, 0, stream>>>(partials, Wfc, bfc, out);
}